// Round 5
// baseline (299.748 us; speedup 1.0000x reference)
//
#include <hip/hip_runtime.h>
#include <hip/hip_bf16.h>
#include <math.h>

typedef __bf16 bf16;
typedef __bf16 bf16x4 __attribute__((ext_vector_type(4)));
typedef __bf16 bf16x8 __attribute__((ext_vector_type(8)));
typedef float f32x4 __attribute__((ext_vector_type(4)));

#define DIM 768
#define HID 3072
#define HID2 1536
#define NLEV 9
#define SEQ 2048
#define ROWS 4096            // BATCH*SEQ
#define MAXPAD 5248          // ROWS + NLEV*128 (rounded)
#define MAXTILES 41          // MAXPAD/128

// ---------------- async global->LDS 16B ----------------
__device__ __forceinline__ void gld16(const void* g, void* l) {
    __builtin_amdgcn_global_load_lds(
        (const __attribute__((address_space(1))) void*)g,
        (__attribute__((address_space(3))) void*)l, 16, 0, 0);
}

// fast tanh-GELU: max |err| vs exact-erf gelu ~5e-4 (inputs here |v|<~4)
__device__ __forceinline__ float fast_gelu(float v) {
    float v2 = v * v;
    float twou = v * (1.59576912f + 0.071354816f * v2);
    float t = __expf(twou);
    return v * t / (t + 1.0f);
}

// ================= PREP bodies =================

__device__ __forceinline__ void ln_body(int row, float* sm,
                                        const float* __restrict__ x,
                                        const float* __restrict__ gamma,
                                        const float* __restrict__ beta,
                                        bf16* __restrict__ xn) {
    int tid = threadIdx.x;
    const float* xr = x + (size_t)row * DIM;
    float v0 = xr[tid], v1 = xr[tid + 256], v2 = xr[tid + 512];
    float s = v0 + v1 + v2;
    float q = v0 * v0 + v1 * v1 + v2 * v2;
    for (int off = 32; off; off >>= 1) {
        s += __shfl_down(s, off, 64);
        q += __shfl_down(q, off, 64);
    }
    int wv = tid >> 6, ln = tid & 63;
    if (ln == 0) { sm[wv] = s; sm[4 + wv] = q; }
    __syncthreads();
    if (tid == 0) {
        float S = sm[0] + sm[1] + sm[2] + sm[3];
        float Q = sm[4] + sm[5] + sm[6] + sm[7];
        float m = S * (1.0f / DIM);
        float var = Q * (1.0f / DIM) - m * m;
        sm[8] = m;
        sm[9] = rsqrtf(var + 1e-5f);
    }
    __syncthreads();
    float m = sm[8], r = sm[9];
    bf16* xo = xn + (size_t)row * DIM;
    xo[tid]       = (bf16)((v0 - m) * r * gamma[tid]       + beta[tid]);
    xo[tid + 256] = (bf16)((v1 - m) * r * gamma[tid + 256] + beta[tid + 256]);
    xo[tid + 512] = (bf16)((v2 - m) * r * gamma[tid + 512] + beta[tid + 512]);
}

// 64x64 tile transpose: fp32 [R][C] -> bf16 [C][R]. sm = 64*65 floats.
__device__ __forceinline__ void transpose_body64(float* sm,
                                                 const float* __restrict__ inb,
                                                 bf16* __restrict__ outb,
                                                 int R, int C, int bx, int by) {
    int tid = threadIdx.x;
    int ty = tid >> 4;            // 0..15
    int tx4 = (tid & 15) * 4;     // col within tile, step 4
#pragma unroll
    for (int p = 0; p < 4; p++) {
        int rloc = p * 16 + ty;
        int row = by * 64 + rloc;
        float4 v = *(const float4*)(inb + (size_t)row * C + bx * 64 + tx4);
        sm[rloc * 65 + tx4 + 0] = v.x;
        sm[rloc * 65 + tx4 + 1] = v.y;
        sm[rloc * 65 + tx4 + 2] = v.z;
        sm[rloc * 65 + tx4 + 3] = v.w;
    }
    __syncthreads();
    int ch = tid & 7;             // 16B chunk along R
    int ocb = tid >> 3;           // 0..31
#pragma unroll
    for (int p = 0; p < 2; p++) {
        int oc = p * 32 + ocb;    // col of tile = out row
        bf16x8 tmp;
#pragma unroll
        for (int k = 0; k < 8; k++) tmp[k] = (bf16)sm[(ch * 8 + k) * 65 + oc];
        *(bf16x8*)(outb + (size_t)(bx * 64 + oc) * R + by * 64 + ch * 8) = tmp;
    }
}

__device__ __forceinline__ void routing_body(float* sm,
                                             const int* __restrict__ levels_info,
                                             const float* __restrict__ lmw,
                                             float* __restrict__ mix,
                                             int* __restrict__ row_index,
                                             int* __restrict__ tile_meta,
                                             float* __restrict__ zbuf) {
    int* cnt = (int*)sm;            // [NLEV]
    int* cur = cnt + NLEV;          // [NLEV]
    int* off = cur + NLEV;          // [NLEV]
    float* mixv = (float*)(off + NLEV);  // [NLEV]
    int tid = threadIdx.x;
    if (tid < NLEV) { cnt[tid] = 0; cur[tid] = 0; }
    __syncthreads();
    for (int s = tid; s < SEQ; s += 256) {
        int d = levels_info[s * 4];
        d = d < 0 ? 0 : (d > 8 ? 8 : d);
        atomicAdd(&cnt[d], 1);
    }
    for (int i = tid; i < MAXPAD; i += 256) row_index[i] = -1;
    if (tid < 16) zbuf[tid] = 0.0f;
    __syncthreads();
    if (tid == 0) {
        float mx = lmw[0];
        for (int l = 1; l < NLEV; l++) mx = fmaxf(mx, lmw[l]);
        float denom = 0.f;
        for (int l = 0; l < NLEV; l++) denom += (float)cnt[l] * expf(lmw[l] - mx);
        float inv = 1.0f / denom;
        int running = 0, t = 0;
        for (int l = 0; l < NLEV; l++) {
            mixv[l] = expf(lmw[l] - mx) * inv;
            off[l] = running;
            int seg = (2 * cnt[l] + 127) & ~127;
            for (int k = 0; k < seg / 128; k++) tile_meta[t++] = l;
            running += seg;
        }
        for (; t < MAXTILES; t++) tile_meta[t] = -1;
    }
    __syncthreads();
    for (int s = tid; s < SEQ; s += 256) {
        int d = levels_info[s * 4];
        d = d < 0 ? 0 : (d > 8 ? 8 : d);
        int p = atomicAdd(&cur[d], 2);
        row_index[off[d] + p]     = s;
        row_index[off[d] + p + 1] = s + SEQ;
        mix[s] = mixv[d];
    }
}

// ---------------- fat prep kernel: routing + LN + all transposes ----------------
__global__ __launch_bounds__(256) void prep_kernel(const float* __restrict__ x,
                                                   const int* __restrict__ levels_info,
                                                   const float* __restrict__ gamma,
                                                   const float* __restrict__ beta,
                                                   const float* __restrict__ W1,
                                                   const float* __restrict__ W2,
                                                   const float* __restrict__ A1,
                                                   const float* __restrict__ A2,
                                                   const float* __restrict__ lmw,
                                                   bf16* __restrict__ Xn,
                                                   bf16* __restrict__ W1t,
                                                   bf16* __restrict__ W2t,
                                                   bf16* __restrict__ A1t,
                                                   bf16* __restrict__ A2t,
                                                   float* __restrict__ mix,
                                                   int* __restrict__ row_index,
                                                   int* __restrict__ tile_meta,
                                                   float* __restrict__ zbuf) {
    __shared__ __align__(16) float sm[64 * 65];
    int bid = blockIdx.x;
    if (bid == 0) { routing_body(sm, levels_info, lmw, mix, row_index, tile_meta, zbuf); return; }
    bid -= 1;
    if (bid < ROWS) { ln_body(bid, sm, x, gamma, beta, Xn); return; }
    bid -= ROWS;
    if (bid < 576) {  // W1 [768,3072] -> [3072,768]: 12 by x 48 bx
        transpose_body64(sm, W1, W1t, DIM, HID, bid % 48, bid / 48);
        return;
    }
    bid -= 576;
    if (bid < 576) {  // W2 [3072,768] -> [768,3072]: 48 by x 12 bx
        transpose_body64(sm, W2, W2t, HID, DIM, bid % 12, bid / 12);
        return;
    }
    bid -= 576;
    if (bid < 2592) {  // A1[lvl] [768,1536] -> [1536,768]: 12 by x 24 bx
        int bz = bid / 288, r = bid % 288;
        transpose_body64(sm, A1 + (size_t)bz * DIM * HID2, A1t + (size_t)bz * DIM * HID2,
                         DIM, HID2, r % 24, r / 24);
        return;
    }
    bid -= 2592;
    {   // A2[lvl] [1536,768] -> [768,1536]: 24 by x 12 bx
        int bz = bid / 288, r = bid % 288;
        transpose_body64(sm, A2 + (size_t)bz * HID2 * DIM, A2t + (size_t)bz * HID2 * DIM,
                         HID2, DIM, r % 12, r / 12);
    }
}

// ---------------- double-buffered GEMM main loop, XOR-swizzled LDS ----------------
__device__ __forceinline__ void gemm_loop_db(const bf16* ga0, const bf16* ga1,
                                             int stepa0, int stepa1,
                                             const bf16* gb0, const bf16* gb1, int stepb,
                                             bf16* As, bf16* Bs,
                                             f32x4 (&acc)[4][4], int ktiles) {
    int tid = threadIdx.x;
    int wv = tid >> 6;
    int lane = tid & 63;
    int wm = wv >> 1, wn = wv & 1;
    int swz = (lane >> 1) & 3;
    int achunk = ((lane >> 4) ^ swz) * 8;
    int aoff = ((wm * 64) + (lane & 15)) * 32 + achunk;
    int boff = ((wn * 64) + (lane & 15)) * 32 + achunk;
    // prologue: stage tile 0 into buffer 0
    gld16(ga0, As + wv * 512);
    gld16(ga1, As + 2048 + wv * 512);
    gld16(gb0, Bs + wv * 512);
    gld16(gb1, Bs + 2048 + wv * 512);
    ga0 += stepa0; ga1 += stepa1; gb0 += stepb; gb1 += stepb;
    for (int kt = 0; kt < ktiles; ++kt) {
        __syncthreads();
        int cur = (kt & 1) << 12;
        int nxt = cur ^ 4096;
        if (kt + 1 < ktiles) {
            gld16(ga0, As + nxt + wv * 512);
            gld16(ga1, As + nxt + 2048 + wv * 512);
            gld16(gb0, Bs + nxt + wv * 512);
            gld16(gb1, Bs + nxt + 2048 + wv * 512);
            ga0 += stepa0; ga1 += stepa1; gb0 += stepb; gb1 += stepb;
        }
        bf16x8 af[4], bfr[4];
#pragma unroll
        for (int i = 0; i < 4; i++) af[i] = *(const bf16x8*)(As + cur + aoff + i * 512);
#pragma unroll
        for (int j = 0; j < 4; j++) bfr[j] = *(const bf16x8*)(Bs + cur + boff + j * 512);
#pragma unroll
        for (int i = 0; i < 4; i++)
#pragma unroll
            for (int j = 0; j < 4; j++)
                acc[i][j] = __builtin_amdgcn_mfma_f32_16x16x32_bf16(af[i], bfr[j], acc[i][j], 0, 0, 0);
    }
}

#define ACC_INIT(acc) \
    _Pragma("unroll") for (int i = 0; i < 4; i++) \
    _Pragma("unroll") for (int j = 0; j < 4; j++) acc[i][j] = (f32x4){0.f, 0.f, 0.f, 0.f};

// producer-side swizzled chunk index for global fetch
#define SWZ_CG(tid) (((tid) & 3) ^ (((tid) >> 3) & 3))

// ---------------- mlp1: gemm1 (H=gelu(Xn@W1+b1)) + agemm1 (HL=relu(gather@A1+a1b)) ----------------
__global__ __launch_bounds__(256) void mlp1_kernel(const bf16* __restrict__ Xn,
                                                   const bf16* __restrict__ W1t,
                                                   const float* __restrict__ b1,
                                                   bf16* __restrict__ H,
                                                   const bf16* __restrict__ A1t,
                                                   const float* __restrict__ a1b,
                                                   const int* __restrict__ row_index,
                                                   const int* __restrict__ tile_meta,
                                                   const bf16* __restrict__ zbuf,
                                                   bf16* __restrict__ HL) {
    __shared__ __align__(16) bf16 As[8192], Bs[8192];
    int bid = blockIdx.x, tid = threadIdx.x;
    int r0 = tid >> 2, cg = SWZ_CG(tid);
    int lane = tid & 63, wv = tid >> 6, wm = wv >> 1, wn = wv & 1;
    f32x4 acc[4][4];
    ACC_INIT(acc);

    if (bid < 768) {
        // ---- gemm1: 32 M x 24 N; mb low bits = bid&7 so each XCD reuses 4 M-strips ----
        int mb = (bid & 7) + 8 * ((bid >> 3) & 3);
        int nb = bid >> 5;
        const bf16* ga0 = Xn + (size_t)(mb * 128 + r0) * DIM + cg * 8;
        const bf16* ga1 = ga0 + (size_t)64 * DIM;
        const bf16* gb0 = W1t + (size_t)(nb * 128 + r0) * DIM + cg * 8;
        const bf16* gb1 = gb0 + (size_t)64 * DIM;
        gemm_loop_db(ga0, ga1, 32, 32, gb0, gb1, 32, As, Bs, acc, DIM / 32);
        int rbase = mb * 128 + wm * 64 + ((lane >> 4) << 2);
        int cbase = nb * 128 + wn * 64 + (lane & 15);
#pragma unroll
        for (int j = 0; j < 4; j++) {
            int c = cbase + j * 16;
            float bias = b1[c];
#pragma unroll
            for (int i = 0; i < 4; i++)
#pragma unroll
                for (int r = 0; r < 4; r++) {
                    int row = rbase + i * 16 + r;
                    float v = acc[i][j][r] + bias;
                    H[(size_t)row * HID + c] = (bf16)fast_gelu(v);
                }
        }
    } else {
        // ---- agemm1: 41 tiles x 12 N-tiles ----
        int t2 = bid - 768;
        int t = t2 % MAXTILES, nb = t2 / MAXTILES;
        int lvl = tile_meta[t];
        if (lvl < 0) return;
        int ridx0 = row_index[t * 128 + r0];
        int ridx1 = row_index[t * 128 + 64 + r0];
        const bf16* ga0 = (ridx0 >= 0) ? (Xn + (size_t)ridx0 * DIM + cg * 8) : zbuf;
        const bf16* ga1 = (ridx1 >= 0) ? (Xn + (size_t)ridx1 * DIM + cg * 8) : zbuf;
        int sa0 = (ridx0 >= 0) ? 32 : 0;
        int sa1 = (ridx1 >= 0) ? 32 : 0;
        const bf16* Bl = A1t + (size_t)lvl * HID2 * DIM;
        const bf16* gb0 = Bl + (size_t)(nb * 128 + r0) * DIM + cg * 8;
        const bf16* gb1 = gb0 + (size_t)64 * DIM;
        gemm_loop_db(ga0, ga1, sa0, sa1, gb0, gb1, 32, As, Bs, acc, DIM / 32);
        int rbase = wm * 64 + ((lane >> 4) << 2);
        int cbase = nb * 128 + wn * 64 + (lane & 15);
#pragma unroll
        for (int j = 0; j < 4; j++) {
            int c = cbase + j * 16;
            float bias = a1b[lvl * HID2 + c];
#pragma unroll
            for (int i = 0; i < 4; i++)
#pragma unroll
                for (int r = 0; r < 4; r++) {
                    int rl = rbase + i * 16 + r;
                    float v = acc[i][j][r] + bias;
                    HL[(size_t)(t * 128 + rl) * HID2 + c] = (bf16)fmaxf(v, 0.0f);
                }
        }
    }
}

// ---------------- mlp2: gemm2 split-K=4 + agemm2 split-K=2 -> bf16 partial buffers ----------------
__global__ __launch_bounds__(256) void mlp2_kernel(const bf16* __restrict__ H,
                                                   const bf16* __restrict__ W2t,
                                                   bf16* __restrict__ part,   // [4][ROWS*DIM]
                                                   const bf16* __restrict__ HL,
                                                   const bf16* __restrict__ A2t,
                                                   const float* __restrict__ a2b,
                                                   const int* __restrict__ row_index,
                                                   const int* __restrict__ tile_meta,
                                                   bf16* __restrict__ apart) { // [2][ROWS*DIM]
    __shared__ __align__(16) bf16 As[8192], Bs[8192];
    int bid = blockIdx.x, tid = threadIdx.x;
    int r0 = tid >> 2, cg = SWZ_CG(tid);
    int lane = tid & 63, wv = tid >> 6, wm = wv >> 1, wn = wv & 1;
    f32x4 acc[4][4];
    ACC_INIT(acc);

    if (bid < 768) {
        // ---- gemm2: 32 M x 6 N x 4 K-splits (K-chunk 768, 24 iters) ----
        int mb = (bid & 7) + 8 * ((bid >> 3) & 3);
        int rest = bid >> 5;        // 0..23
        int nb = rest % 6;
        int ks = rest / 6;          // 0..3
        const bf16* ga0 = H + (size_t)(mb * 128 + r0) * HID + ks * 768 + cg * 8;
        const bf16* ga1 = ga0 + (size_t)64 * HID;
        const bf16* gb0 = W2t + (size_t)(nb * 128 + r0) * HID + ks * 768 + cg * 8;
        const bf16* gb1 = gb0 + (size_t)64 * HID;
        gemm_loop_db(ga0, ga1, 32, 32, gb0, gb1, 32, As, Bs, acc, 24);
        bf16* pk = part + (size_t)ks * ROWS * DIM;
        int rbase = mb * 128 + wm * 64 + ((lane >> 4) << 2);
        int cbase = nb * 128 + wn * 64 + (lane & 15);
#pragma unroll
        for (int j = 0; j < 4; j++) {
            int c = cbase + j * 16;
#pragma unroll
            for (int i = 0; i < 4; i++)
#pragma unroll
                for (int r = 0; r < 4; r++) {
                    int row = rbase + i * 16 + r;
                    pk[(size_t)row * DIM + c] = (bf16)acc[i][j][r];
                }
        }
    } else {
        // ---- agemm2: 41 tiles x 6 N x 2 K-splits (K-chunk 768, 24 iters) ----
        int t2 = bid - 768;
        int t = t2 % MAXTILES;
        int rest = t2 / MAXTILES;   // 0..11
        int nb = rest % 6;
        int ks = rest / 6;          // 0..1
        int lvl = tile_meta[t];
        if (lvl < 0) return;
        const bf16* ga0 = HL + (size_t)(t * 128 + r0) * HID2 + ks * 768 + cg * 8;
        const bf16* ga1 = ga0 + (size_t)64 * HID2;
        const bf16* Bl = A2t + (size_t)lvl * DIM * HID2;
        const bf16* gb0 = Bl + (size_t)(nb * 128 + r0) * HID2 + ks * 768 + cg * 8;
        const bf16* gb1 = gb0 + (size_t)64 * HID2;
        gemm_loop_db(ga0, ga1, 32, 32, gb0, gb1, 32, As, Bs, acc, 24);
        bf16* apk = apart + (size_t)ks * ROWS * DIM;
        int rbase = wm * 64 + ((lane >> 4) << 2);
        int cbase = nb * 128 + wn * 64 + (lane & 15);
#pragma unroll
        for (int i = 0; i < 4; i++)
#pragma unroll
            for (int r = 0; r < 4; r++) {
                int rl = rbase + i * 16 + r;
                int rg = row_index[t * 128 + rl];
                if (rg >= 0) {
#pragma unroll
                    for (int j = 0; j < 4; j++) {
                        int c = cbase + j * 16;
                        float v = acc[i][j][r] + (ks == 0 ? a2b[lvl * DIM + c] : 0.0f);
                        apk[(size_t)rg * DIM + c] = (bf16)v;
                    }
                }
            }
    }
}

// ---------------- combine: out = (1-mix)*(Σ4 part + b2) + mix*(Σ2 apart) ----------------
__global__ __launch_bounds__(256) void combine_kernel(const bf16* __restrict__ part,
                                                      const bf16* __restrict__ apart,
                                                      const float* __restrict__ b2,
                                                      const float* __restrict__ mix,
                                                      float* __restrict__ out) {
    int i = blockIdx.x * 256 + threadIdx.x;
    int base = i * 4;
    int row = base / DIM;
    int c = base - row * DIM;
    float mx = mix[row & (SEQ - 1)];
    bf16x4 p0 = *(const bf16x4*)(part + base);
    bf16x4 p1 = *(const bf16x4*)(part + (size_t)1 * ROWS * DIM + base);
    bf16x4 p2 = *(const bf16x4*)(part + (size_t)2 * ROWS * DIM + base);
    bf16x4 p3 = *(const bf16x4*)(part + (size_t)3 * ROWS * DIM + base);
    bf16x4 a0 = *(const bf16x4*)(apart + base);
    bf16x4 a1 = *(const bf16x4*)(apart + (size_t)1 * ROWS * DIM + base);
    float4 o;
    float* po = &o.x;
#pragma unroll
    for (int k = 0; k < 4; k++) {
        float main_v = (float)p0[k] + (float)p1[k] + (float)p2[k] + (float)p3[k] + b2[c + k];
        float ap_v = (float)a0[k] + (float)a1[k];
        po[k] = (1.0f - mx) * main_v + mx * ap_v;
    }
    *(float4*)(out + base) = o;
}

// ---------------- launch ----------------
extern "C" void kernel_launch(void* const* d_in, const int* in_sizes, int n_in,
                              void* d_out, int out_size, void* d_ws, size_t ws_size,
                              hipStream_t stream) {
    const float* x    = (const float*)d_in[0];
    const int* levels = (const int*)d_in[1];
    const float* gamma= (const float*)d_in[2];
    const float* beta = (const float*)d_in[3];
    const float* W1   = (const float*)d_in[4];
    const float* b1   = (const float*)d_in[5];
    const float* W2   = (const float*)d_in[6];
    const float* b2   = (const float*)d_in[7];
    const float* A1   = (const float*)d_in[8];
    const float* a1b  = (const float*)d_in[9];
    const float* A2   = (const float*)d_in[10];
    const float* a2b  = (const float*)d_in[11];
    const float* lmw  = (const float*)d_in[12];
    float* out = (float*)d_out;

    char* p = (char*)d_ws;
    auto alloc = [&](size_t bytes) {
        char* r = p;
        p += (bytes + 255) & ~(size_t)255;
        return r;
    };
    bf16* Xn   = (bf16*)alloc((size_t)ROWS * DIM * 2);
    bf16* W1t  = (bf16*)alloc((size_t)HID * DIM * 2);
    bf16* W2t  = (bf16*)alloc((size_t)DIM * HID * 2);
    bf16* A1t  = (bf16*)alloc((size_t)NLEV * HID2 * DIM * 2);
    bf16* A2t  = (bf16*)alloc((size_t)NLEV * DIM * HID2 * 2);
    bf16* H    = (bf16*)alloc((size_t)ROWS * HID * 2);
    bf16* HL   = (bf16*)alloc((size_t)MAXPAD * HID2 * 2);
    bf16* part = (bf16*)alloc((size_t)4 * ROWS * DIM * 2);
    bf16* apart= (bf16*)alloc((size_t)2 * ROWS * DIM * 2);
    float* mix = (float*)alloc(SEQ * 4);
    int* row_index = (int*)alloc(MAXPAD * 4);
    int* tile_meta = (int*)alloc(MAXTILES * 4);
    float* zbuf    = (float*)alloc(64);

    // prep: routing(1) + LN(4096) + W1(576) + W2(576) + A1(2592) + A2(2592)
    prep_kernel<<<dim3(1 + ROWS + 576 + 576 + 2592 + 2592), dim3(256), 0, stream>>>(
        x, levels, gamma, beta, W1, W2, A1, A2, lmw,
        Xn, W1t, W2t, A1t, A2t, mix, row_index, tile_meta, zbuf);

    // mlp1: gemm1 (768) + agemm1 (492)
    mlp1_kernel<<<dim3(768 + MAXTILES * 12), dim3(256), 0, stream>>>(
        Xn, W1t, b1, H, A1t, a1b, row_index, tile_meta, (const bf16*)zbuf, HL);

    // mlp2: gemm2 splitK4 (768) + agemm2 splitK2 (492) -> partial buffers
    mlp2_kernel<<<dim3(768 + MAXTILES * 12), dim3(256), 0, stream>>>(
        H, W2t, part, HL, A2t, a2b, row_index, tile_meta, apart);

    // combine: blend main + adapter into out
    combine_kernel<<<dim3(ROWS * DIM / 1024), dim3(256), 0, stream>>>(
        part, apart, b2, mix, out);
}